// Round 20
// baseline (191.978 us; speedup 1.0000x reference)
//
#include <hip/hip_runtime.h>
#include <math.h>

// Problem constants (match reference)
#define TSEQ 32
#define HID  4096
#define NH   32
#define NKVH 8
#define HD   128
#define NCOL 6144           // NH*HD + 2*NKVH*HD
#define BSZ  16
#define MAXBLK 128
#define CH   256            // attention context chunk (4 waves x 64 positions)
#define NKC  32             // split-K chunks for GEMMs (k=128 each)

// workspace layout (float offsets)
#define N_PART   (NKC*32*6144)       // qkv split-K partials (reused for proj partials)
#define OFF_Q    (N_PART)
#define OFF_KN   (OFF_Q  + 131072)
#define OFF_VN   (OFF_KN + 32768)
#define OFF_AT   (OFF_VN + 32768)
#define OFF_AP   (OFF_AT + 131072)   // attn partials [32][8][8][520]

// nontemporal float4 helpers (partial store/reload streams only)
typedef float vfloat4 __attribute__((ext_vector_type(4)));
__device__ __forceinline__ float4 ntload4(const float* p) {
  vfloat4 v = __builtin_nontemporal_load((const vfloat4*)p);
  return make_float4(v[0], v[1], v[2], v[3]);
}
__device__ __forceinline__ void ntstore4(float* p, float4 s) {
  vfloat4 v = {s.x, s.y, s.z, s.w};
  __builtin_nontemporal_store(v, (vfloat4*)p);
}

// ---------------- kernel 1: QKV split-K GEMM ----------------
// R20: 512 threads = 8 waves x 4 rows; lane covers 8 cols (2x float4 W loads).
// Same occupancy & VGPR as R13, DOUBLE per-wave W bytes in flight.
// grid (12 col-tiles of 512, 32 k-chunks)
__global__ __launch_bounds__(512) void qkv_kernel(
    const float* __restrict__ hs, const float* __restrict__ Wq,
    const float* __restrict__ Wk, const float* __restrict__ Wv,
    float* __restrict__ part) {
  const int lane = threadIdx.x & 63;
  const int wu = __builtin_amdgcn_readfirstlane(threadIdx.x >> 6);  // 0..7
  const int col0 = blockIdx.x * 512 + lane * 8;   // 8 consecutive cols per lane
  const int kc = blockIdx.y;
  const int k0 = kc * 128;
  const float* W; int ldw, jloc;
  if (col0 < 4096)      { W = Wq; ldw = 4096; jloc = col0; }          // tiles 0-7
  else if (col0 < 5120) { W = Wk; ldw = 1024; jloc = col0 - 4096; }   // tiles 8-9
  else                  { W = Wv; ldw = 1024; jloc = col0 - 5120; }   // tiles 10-11
  float4 accA[4], accB[4];
#pragma unroll
  for (int r = 0; r < 4; ++r) {
    accA[r] = make_float4(0.f, 0.f, 0.f, 0.f);
    accB[r] = make_float4(0.f, 0.f, 0.f, 0.f);
  }
  const float* wp = W + (size_t)k0 * ldw + jloc;
  const float* hp = hs + (size_t)(wu * 4) * HID + k0;   // 4 rows, uniform -> s_load
#pragma unroll 4
  for (int kk = 0; kk < 128; ++kk) {
    float4 wa = *(const float4*)(wp + (size_t)kk * ldw);
    float4 wb = *(const float4*)(wp + (size_t)kk * ldw + 4);
#pragma unroll
    for (int r = 0; r < 4; ++r) {
      float h = hp[r * HID + kk];
      accA[r].x = fmaf(h, wa.x, accA[r].x);
      accA[r].y = fmaf(h, wa.y, accA[r].y);
      accA[r].z = fmaf(h, wa.z, accA[r].z);
      accA[r].w = fmaf(h, wa.w, accA[r].w);
      accB[r].x = fmaf(h, wb.x, accB[r].x);
      accB[r].y = fmaf(h, wb.y, accB[r].y);
      accB[r].z = fmaf(h, wb.z, accB[r].z);
      accB[r].w = fmaf(h, wb.w, accB[r].w);
    }
  }
  float* o = part + (size_t)kc * 32 * NCOL + (size_t)(wu * 4) * NCOL + blockIdx.x * 512 + lane * 8;
#pragma unroll
  for (int r = 0; r < 4; ++r) {
    ntstore4(o + (size_t)r * NCOL, accA[r]);
    ntstore4(o + (size_t)r * NCOL + 4, accB[r]);
  }
}

// ---------------- kernel 2: reduce partials + RoPE + split q/k/v (R19-exact) ----------------
__global__ __launch_bounds__(256) void rope_kernel(
    const float* __restrict__ part, const int* __restrict__ ctxl,
    float* __restrict__ q, float* __restrict__ kn, float* __restrict__ vn) {
  const int t = blockIdx.x;
  const int col = (blockIdx.y * 256 + threadIdx.x) * 4;
  float4 sum = make_float4(0.f, 0.f, 0.f, 0.f);
  const float* p = part + (size_t)t * NCOL + col;
#pragma unroll
  for (int c = 0; c < NKC; ++c) {
    float4 v = ntload4(p + (size_t)c * 32 * NCOL);       // single-use: nt
    sum.x += v.x; sum.y += v.y; sum.z += v.z; sum.w += v.w;
  }
  __shared__ float lds[1024];
  __shared__ float tcs[64], tsn[64];
  *(float4*)&lds[threadIdx.x * 4] = sum;
  if (threadIdx.x < 64) {
    double pos = (double)(ctxl[t] - 1);
    double inv = exp(-(double)threadIdx.x * (9.210340371976184 / 64.0));
    double f = pos * inv;
    tcs[threadIdx.x] = (float)cos(f);
    tsn[threadIdx.x] = (float)sin(f);
  }
  __syncthreads();
  float out[4] = {sum.x, sum.y, sum.z, sum.w};
  if (col < 5120) {   // uniform per block
#pragma unroll
    for (int j = 0; j < 4; ++j) {
      int d = (col + j) & 127;
      int i = d & 63;
      float partner = lds[(threadIdx.x * 4 + j) ^ 64];
      float c0 = tcs[i], s0 = tsn[i];
      out[j] = (d < 64) ? (out[j] * c0 - partner * s0) : (out[j] * c0 + partner * s0);
    }
  }
  float4 o4 = make_float4(out[0], out[1], out[2], out[3]);
  if (col < 4096)      *(float4*)(q  + (size_t)t * 4096 + col) = o4;
  else if (col < 5120) *(float4*)(kn + (size_t)t * 1024 + (col - 4096)) = o4;
  else                 *(float4*)(vn + (size_t)t * 1024 + (col - 5120)) = o4;
}

// ---------------- kernel 3: flash-decoding attention partials (R19-exact) ----------------
__global__ __launch_bounds__(256) void attn_kernel(
    const float* __restrict__ kcache, const float* __restrict__ vcache,
    const int* __restrict__ bt, const int* __restrict__ ctxl,
    const float* __restrict__ q, const float* __restrict__ kn,
    const float* __restrict__ vn, float* __restrict__ part) {
  const int t = blockIdx.x, kvh = blockIdx.y, ch = blockIdx.z;
  const int ctx = ctxl[t];
  const int s0 = ch * CH;
  if (s0 >= ctx) return;
  const int ns = min(CH, ctx - s0);
  const int tid = threadIdx.x;
  const int w = tid >> 6, lane = tid & 63;

  __shared__ float qs[4][128];
  __shared__ int   bts[16];          // this chunk's 16 block-table entries
  __shared__ float pl[4][64][4];     // [wave][within-wave slot][head]
  __shared__ float om[4][4], ol[4][4];
  __shared__ float oacc[4][4][128];  // [wave][head][d]

  for (int i = tid; i < 512; i += 256)
    qs[i >> 7][i & 127] = q[((size_t)t * NH + kvh * 4 + (i >> 7)) * HD + (i & 127)];
  if (tid < 16) bts[tid] = bt[t * MAXBLK + ch * 16 + tid];   // chunk-local table
  __syncthreads();

  const float* knp = kn + ((size_t)t * NKVH + kvh) * HD;
  const float* vnp = vn + ((size_t)t * NKVH + kvh) * HD;

  // ---- pass 1: 4 positions per wave-step, 16 lanes per position (coalesced rows) ----
  const int j16 = lane & 15;           // dim-slice: covers dims j16*8 .. j16*8+7
  const int pp  = lane >> 4;           // position within step (0..3)
  float4 qa[4], qb[4];
#pragma unroll
  for (int h = 0; h < 4; ++h) {
    qa[h] = *(const float4*)(&qs[h][j16 * 8]);
    qb[h] = *(const float4*)(&qs[h][j16 * 8 + 4]);
  }
#pragma unroll 4
  for (int i = 0; i < 16; ++i) {
    const int ls   = i * 4 + pp;            // within-wave slot 0..63
    const int slp  = w * 64 + ls;           // chunk-local slot 0..255
    const int spos = s0 + slp;              // global position
    const float* kp2;
    {
      int phys = bts[slp >> 4];
      const float* kreal = kcache + (((size_t)phys * BSZ + (slp & 15)) * NKVH + kvh) * HD;
      kp2 = (spos == ctx - 1) ? knp : kreal;  // invalid rows load in-bounds garbage (masked later)
    }
    float4 ka = *(const float4*)(kp2 + j16 * 8);
    float4 kb = *(const float4*)(kp2 + j16 * 8 + 4);
    float d0, d1, d2, d3;
    d0 = ka.x*qa[0].x + ka.y*qa[0].y + ka.z*qa[0].z + ka.w*qa[0].w
       + kb.x*qb[0].x + kb.y*qb[0].y + kb.z*qb[0].z + kb.w*qb[0].w;
    d1 = ka.x*qa[1].x + ka.y*qa[1].y + ka.z*qa[1].z + ka.w*qa[1].w
       + kb.x*qb[1].x + kb.y*qb[1].y + kb.z*qb[1].z + kb.w*qb[1].w;
    d2 = ka.x*qa[2].x + ka.y*qa[2].y + ka.z*qa[2].z + ka.w*qa[2].w
       + kb.x*qb[2].x + kb.y*qb[2].y + kb.z*qb[2].z + kb.w*qb[2].w;
    d3 = ka.x*qa[3].x + ka.y*qa[3].y + ka.z*qa[3].z + ka.w*qa[3].w
       + kb.x*qb[3].x + kb.y*qb[3].y + kb.z*qb[3].z + kb.w*qb[3].w;
#pragma unroll
    for (int m = 1; m < 16; m <<= 1) {
      d0 += __shfl_xor(d0, m, 64);
      d1 += __shfl_xor(d1, m, 64);
      d2 += __shfl_xor(d2, m, 64);
      d3 += __shfl_xor(d3, m, 64);
    }
    if (j16 == 0) *(float4*)&pl[w][ls][0] = make_float4(d0, d1, d2, d3);
  }

  // ---- softmax over 64 positions (reads raw scores from pl; wave-local DS order) ----
  const int sl = w * 64 + lane;
  const bool valid = sl < ns;
  const float scale = 0.08838834764831845f;
  float4 sraw = *(const float4*)&pl[w][lane][0];
  float sc0 = valid ? sraw.x * scale : -INFINITY;
  float sc1 = valid ? sraw.y * scale : -INFINITY;
  float sc2 = valid ? sraw.z * scale : -INFINITY;
  float sc3 = valid ? sraw.w * scale : -INFINITY;

  float m0 = sc0, m1 = sc1, m2 = sc2, m3 = sc3;
#pragma unroll
  for (int mk = 1; mk < 64; mk <<= 1) {
    m0 = fmaxf(m0, __shfl_xor(m0, mk, 64));
    m1 = fmaxf(m1, __shfl_xor(m1, mk, 64));
    m2 = fmaxf(m2, __shfl_xor(m2, mk, 64));
    m3 = fmaxf(m3, __shfl_xor(m3, mk, 64));
  }
  float p0 = __expf(sc0 - fmaxf(m0, -3e38f));
  float p1 = __expf(sc1 - fmaxf(m1, -3e38f));
  float p2 = __expf(sc2 - fmaxf(m2, -3e38f));
  float p3 = __expf(sc3 - fmaxf(m3, -3e38f));
  float l0 = p0, l1 = p1, l2 = p2, l3 = p3;
#pragma unroll
  for (int mk = 1; mk < 64; mk <<= 1) {
    l0 += __shfl_xor(l0, mk, 64);
    l1 += __shfl_xor(l1, mk, 64);
    l2 += __shfl_xor(l2, mk, 64);
    l3 += __shfl_xor(l3, mk, 64);
  }
  *(float4*)&pl[w][lane][0] = make_float4(p0, p1, p2, p3);
  if (lane == 0) {
    om[w][0] = m0; om[w][1] = m1; om[w][2] = m2; om[w][3] = m3;
    ol[w][0] = l0; ol[w][1] = l1; ol[w][2] = l2; ol[w][3] = l3;
  }

  // ---- pass 2: two rows per wave-iter, float4 V loads ----
  const int rh = lane >> 5;
  const int dq = (lane & 31) * 4;
  float a0x=0.f,a0y=0.f,a0z=0.f,a0w=0.f;
  float a1x=0.f,a1y=0.f,a1z=0.f,a1w=0.f;
  float a2x=0.f,a2y=0.f,a2z=0.f,a2w=0.f;
  float a3x=0.f,a3y=0.f,a3z=0.f,a3w=0.f;
  {
    int nsw = ns - w * 64;
    if (nsw > 0) {
      const int sp = (ctx - 1) - (s0 + w * 64);   // special slot, wave-local (may be OOR)
      for (int b4 = 0; b4 < 4; ++b4) {
        int base = b4 * 16;
        if (base >= nsw) break;
        const float* vbase = vcache + (((size_t)bts[w * 4 + b4] * BSZ) * NKVH + kvh) * HD;
#pragma unroll
        for (int j = 0; j < 16; j += 2) {
          int row = base + j + rh;                 // p=0 beyond ns -> garbage*0 OK
          const float* vp = (row == sp) ? vnp : (vbase + (size_t)(j + rh) * (NKVH * HD));
          float4 v4 = *(const float4*)(vp + dq);
          float4 p4 = *(const float4*)&pl[w][row][0];
          a0x = fmaf(p4.x, v4.x, a0x); a0y = fmaf(p4.x, v4.y, a0y);
          a0z = fmaf(p4.x, v4.z, a0z); a0w = fmaf(p4.x, v4.w, a0w);
          a1x = fmaf(p4.y, v4.x, a1x); a1y = fmaf(p4.y, v4.y, a1y);
          a1z = fmaf(p4.y, v4.z, a1z); a1w = fmaf(p4.y, v4.w, a1w);
          a2x = fmaf(p4.z, v4.x, a2x); a2y = fmaf(p4.z, v4.y, a2y);
          a2z = fmaf(p4.z, v4.z, a2z); a2w = fmaf(p4.z, v4.w, a2w);
          a3x = fmaf(p4.w, v4.x, a3x); a3y = fmaf(p4.w, v4.y, a3y);
          a3z = fmaf(p4.w, v4.z, a3z); a3w = fmaf(p4.w, v4.w, a3w);
        }
      }
    }
  }
  a0x += __shfl_xor(a0x, 32, 64); a0y += __shfl_xor(a0y, 32, 64);
  a0z += __shfl_xor(a0z, 32, 64); a0w += __shfl_xor(a0w, 32, 64);
  a1x += __shfl_xor(a1x, 32, 64); a1y += __shfl_xor(a1y, 32, 64);
  a1z += __shfl_xor(a1z, 32, 64); a1w += __shfl_xor(a1w, 32, 64);
  a2x += __shfl_xor(a2x, 32, 64); a2y += __shfl_xor(a2y, 32, 64);
  a2z += __shfl_xor(a2z, 32, 64); a2w += __shfl_xor(a2w, 32, 64);
  a3x += __shfl_xor(a3x, 32, 64); a3y += __shfl_xor(a3y, 32, 64);
  a3z += __shfl_xor(a3z, 32, 64); a3w += __shfl_xor(a3w, 32, 64);
  if (rh == 0) {
    *(float4*)&oacc[w][0][dq] = make_float4(a0x, a0y, a0z, a0w);
    *(float4*)&oacc[w][1][dq] = make_float4(a1x, a1y, a1z, a1w);
    *(float4*)&oacc[w][2][dq] = make_float4(a2x, a2y, a2z, a2w);
    *(float4*)&oacc[w][3][dq] = make_float4(a3x, a3y, a3z, a3w);
  }
  __syncthreads();

  // ---- merge 4 wave-partials, write chunk partial ----
  float* pp2 = part + ((size_t)(t * NKVH + kvh) * 8 + ch) * 520;
  {
    const int g = tid >> 6, d0 = (tid & 63) * 2;
    float mw0 = om[0][g], mw1 = om[1][g], mw2 = om[2][g], mw3 = om[3][g];
    float M = fmaxf(fmaxf(mw0, mw1), fmaxf(mw2, mw3));
    float Ms = fmaxf(M, -3e38f);
    float e0 = __expf(fmaxf(mw0, -3e38f) - Ms);
    float e1 = __expf(fmaxf(mw1, -3e38f) - Ms);
    float e2 = __expf(fmaxf(mw2, -3e38f) - Ms);
    float e3 = __expf(fmaxf(mw3, -3e38f) - Ms);
    float ox = e0*oacc[0][g][d0]   + e1*oacc[1][g][d0]   + e2*oacc[2][g][d0]   + e3*oacc[3][g][d0];
    float oy = e0*oacc[0][g][d0+1] + e1*oacc[1][g][d0+1] + e2*oacc[2][g][d0+1] + e3*oacc[3][g][d0+1];
    *(float2*)(pp2 + 8 + g * 128 + d0) = make_float2(ox, oy);
    if ((tid & 63) == 0) {
      pp2[g]     = M;
      pp2[4 + g] = e0*ol[0][g] + e1*ol[1][g] + e2*ol[2][g] + e3*ol[3][g];
    }
  }
}

// ---------------- kernel 4: combine chunk partials (R19-exact) ----------------
__global__ __launch_bounds__(128) void combine_kernel(
    const float* __restrict__ part, const int* __restrict__ ctxl,
    float* __restrict__ attn) {
  const int t = blockIdx.x, kvh = blockIdx.y;
  const int nc = (ctxl[t] + CH - 1) / CH;
  const int d = threadIdx.x;
#pragma unroll
  for (int g = 0; g < 4; ++g) {
    float m = -INFINITY;
    for (int c = 0; c < nc; ++c)
      m = fmaxf(m, part[((size_t)(t * NKVH + kvh) * 8 + c) * 520 + g]);
    float l = 0.f, o = 0.f;
    for (int c = 0; c < nc; ++c) {
      const float* pp = part + ((size_t)(t * NKVH + kvh) * 8 + c) * 520;
      float scl = __expf(pp[g] - m);
      l += pp[4 + g] * scl;
      o += pp[8 + g * 128 + d] * scl;
    }
    attn[((size_t)t * NH + kvh * 4 + g) * HD + d] = o / l;
  }
}

// ---------------- kernel 5: output projection split-K GEMM ----------------
// R20: 512 threads = 8 waves x 4 rows; lane covers 8 cols; grid (8, 32)
__global__ __launch_bounds__(512) void proj_kernel(
    const float* __restrict__ attn, const float* __restrict__ Wo,
    float* __restrict__ part) {
  const int lane = threadIdx.x & 63;
  const int wu = __builtin_amdgcn_readfirstlane(threadIdx.x >> 6);
  const int col0 = blockIdx.x * 512 + lane * 8;
  const int kc = blockIdx.y;
  const int k0 = kc * 128;
  float4 accA[4], accB[4];
#pragma unroll
  for (int r = 0; r < 4; ++r) {
    accA[r] = make_float4(0.f, 0.f, 0.f, 0.f);
    accB[r] = make_float4(0.f, 0.f, 0.f, 0.f);
  }
  const float* wp = Wo + (size_t)k0 * 4096 + col0;
  const float* hp = attn + (size_t)(wu * 4) * 4096 + k0;
#pragma unroll 4
  for (int kk = 0; kk < 128; ++kk) {
    float4 wa = *(const float4*)(wp + (size_t)kk * 4096);
    float4 wb = *(const float4*)(wp + (size_t)kk * 4096 + 4);
#pragma unroll
    for (int r = 0; r < 4; ++r) {
      float h = hp[r * 4096 + kk];
      accA[r].x = fmaf(h, wa.x, accA[r].x);
      accA[r].y = fmaf(h, wa.y, accA[r].y);
      accA[r].z = fmaf(h, wa.z, accA[r].z);
      accA[r].w = fmaf(h, wa.w, accA[r].w);
      accB[r].x = fmaf(h, wb.x, accB[r].x);
      accB[r].y = fmaf(h, wb.y, accB[r].y);
      accB[r].z = fmaf(h, wb.z, accB[r].z);
      accB[r].w = fmaf(h, wb.w, accB[r].w);
    }
  }
  float* o = part + (size_t)kc * 32 * 4096 + (size_t)(wu * 4) * 4096 + blockIdx.x * 512 + lane * 8;
#pragma unroll
  for (int r = 0; r < 4; ++r) {
    ntstore4(o + (size_t)r * 4096, accA[r]);
    ntstore4(o + (size_t)r * 4096 + 4, accB[r]);
  }
}

// ---------------- kernel 6: reduce proj partials -> out (R19-exact) ----------------
__global__ __launch_bounds__(256) void reduce_out(
    const float* __restrict__ part, float* __restrict__ out) {
  const int t = blockIdx.x;
  const int col = (blockIdx.y * 256 + threadIdx.x) * 4;
  float4 s0 = make_float4(0.f,0.f,0.f,0.f), s1 = make_float4(0.f,0.f,0.f,0.f);
  const float* p = part + (size_t)t * 4096 + col;
#pragma unroll
  for (int c = 0; c < NKC; c += 2) {
    float4 a = ntload4(p + (size_t)c * 32 * 4096);
    float4 b = ntload4(p + (size_t)(c + 1) * 32 * 4096);
    s0.x += a.x; s0.y += a.y; s0.z += a.z; s0.w += a.w;
    s1.x += b.x; s1.y += b.y; s1.z += b.z; s1.w += b.w;
  }
  float4 s = make_float4(s0.x + s1.x, s0.y + s1.y, s0.z + s1.z, s0.w + s1.w);
  *(float4*)(out + (size_t)t * 4096 + col) = s;
}

extern "C" void kernel_launch(void* const* d_in, const int* in_sizes, int n_in,
                              void* d_out, int out_size, void* d_ws, size_t ws_size,
                              hipStream_t stream) {
  const float* hs = (const float*)d_in[0];
  const float* Wq = (const float*)d_in[1];
  const float* Wk = (const float*)d_in[2];
  const float* Wv = (const float*)d_in[3];
  const float* Wo = (const float*)d_in[4];
  const float* kc = (const float*)d_in[5];
  const float* vc = (const float*)d_in[6];
  const int*   bt = (const int*)d_in[7];
  const int*   cl = (const int*)d_in[8];
  float* out = (float*)d_out;
  float* ws  = (float*)d_ws;

  float* part = ws;
  float* q    = ws + OFF_Q;
  float* kn   = ws + OFF_KN;
  float* vn   = ws + OFF_VN;
  float* at   = ws + OFF_AT;
  float* ap   = ws + OFF_AP;

  qkv_kernel<<<dim3(12, NKC), 512, 0, stream>>>(hs, Wq, Wk, Wv, part);
  rope_kernel<<<dim3(32, 6), 256, 0, stream>>>(part, cl, q, kn, vn);
  attn_kernel<<<dim3(32, 8, 8), 256, 0, stream>>>(kc, vc, bt, cl, q, kn, vn, ap);
  combine_kernel<<<dim3(32, 8), 128, 0, stream>>>(ap, cl, at);
  proj_kernel<<<dim3(8, NKC), 512, 0, stream>>>(at, Wo, part);
  reduce_out<<<dim3(32, 4), 256, 0, stream>>>(part, out);
}

// Round 21
// 159.118 us; speedup vs baseline: 1.2065x; 1.2065x over previous
//
#include <hip/hip_runtime.h>
#include <math.h>

// Problem constants (match reference)
#define TSEQ 32
#define HID  4096
#define NH   32
#define NKVH 8
#define HD   128
#define NCOL 6144           // NH*HD + 2*NKVH*HD
#define BSZ  16
#define MAXBLK 128
#define CH   256            // attention context chunk (4 waves x 64 positions)
#define NKC  32             // split-K chunks for GEMMs (k=128 each)

// workspace layout (float offsets)
#define N_PART   (NKC*32*6144)       // qkv split-K partials (reused for proj partials)
#define OFF_Q    (N_PART)
#define OFF_KN   (OFF_Q  + 131072)
#define OFF_VN   (OFF_KN + 32768)
#define OFF_AT   (OFF_VN + 32768)
#define OFF_AP   (OFF_AT + 131072)   // attn partials [32][8][8][520]

// nontemporal float4 helpers (partial store/reload streams only)
typedef float vfloat4 __attribute__((ext_vector_type(4)));
__device__ __forceinline__ float4 ntload4(const float* p) {
  vfloat4 v = __builtin_nontemporal_load((const vfloat4*)p);
  return make_float4(v[0], v[1], v[2], v[3]);
}
__device__ __forceinline__ void ntstore4(float* p, float4 s) {
  vfloat4 v = {s.x, s.y, s.z, s.w};
  __builtin_nontemporal_store(v, (vfloat4*)p);
}

// ---------------- kernel 1: QKV split-K GEMM (R19-exact: best known) ----------------
// block 256 (4 waves x 8 rows x 256 cols), k-chunk 128; grid (24 col-tiles, 32 k-chunks)
__global__ __launch_bounds__(256) void qkv_kernel(
    const float* __restrict__ hs, const float* __restrict__ Wq,
    const float* __restrict__ Wk, const float* __restrict__ Wv,
    float* __restrict__ part) {
  const int lane = threadIdx.x & 63;
  const int wu = __builtin_amdgcn_readfirstlane(threadIdx.x >> 6);  // wave id, SGPR
  const int col0 = blockIdx.x * 256 + lane * 4;
  const int kc = blockIdx.y;
  const int k0 = kc * 128;
  const float* W; int ldw, jloc;
  if (col0 < 4096)      { W = Wq; ldw = 4096; jloc = col0; }
  else if (col0 < 5120) { W = Wk; ldw = 1024; jloc = col0 - 4096; }
  else                  { W = Wv; ldw = 1024; jloc = col0 - 5120; }
  float4 acc[8];
#pragma unroll
  for (int r = 0; r < 8; ++r) acc[r] = make_float4(0.f, 0.f, 0.f, 0.f);
  const float* wp = W + (size_t)k0 * ldw + jloc;
  const float* hp = hs + (size_t)(wu * 8) * HID + k0;   // rows 8w..8w+7, uniform -> s_load
#pragma unroll 4
  for (int kk = 0; kk < 128; ++kk) {
    float4 w4 = *(const float4*)(wp + (size_t)kk * ldw);   // plain load
#pragma unroll
    for (int r = 0; r < 8; ++r) {
      float h = hp[r * HID + kk];
      acc[r].x = fmaf(h, w4.x, acc[r].x);
      acc[r].y = fmaf(h, w4.y, acc[r].y);
      acc[r].z = fmaf(h, w4.z, acc[r].z);
      acc[r].w = fmaf(h, w4.w, acc[r].w);
    }
  }
  float* o = part + (size_t)kc * 32 * NCOL + (size_t)(wu * 8) * NCOL + blockIdx.x * 256 + lane * 4;
#pragma unroll
  for (int r = 0; r < 8; ++r) ntstore4(o + (size_t)r * NCOL, acc[r]);
}

// ---------------- kernel 2: reduce partials + RoPE + split q/k/v ----------------
__global__ __launch_bounds__(256) void rope_kernel(
    const float* __restrict__ part, const int* __restrict__ ctxl,
    float* __restrict__ q, float* __restrict__ kn, float* __restrict__ vn) {
  const int t = blockIdx.x;
  const int col = (blockIdx.y * 256 + threadIdx.x) * 4;
  float4 sum = make_float4(0.f, 0.f, 0.f, 0.f);
  const float* p = part + (size_t)t * NCOL + col;
#pragma unroll
  for (int c = 0; c < NKC; ++c) {
    float4 v = ntload4(p + (size_t)c * 32 * NCOL);       // single-use: nt
    sum.x += v.x; sum.y += v.y; sum.z += v.z; sum.w += v.w;
  }
  __shared__ float lds[1024];
  __shared__ float tcs[64], tsn[64];
  *(float4*)&lds[threadIdx.x * 4] = sum;
  if (threadIdx.x < 64) {
    double pos = (double)(ctxl[t] - 1);
    double inv = exp(-(double)threadIdx.x * (9.210340371976184 / 64.0));
    double f = pos * inv;
    tcs[threadIdx.x] = (float)cos(f);
    tsn[threadIdx.x] = (float)sin(f);
  }
  __syncthreads();
  float out[4] = {sum.x, sum.y, sum.z, sum.w};
  if (col < 5120) {   // uniform per block
#pragma unroll
    for (int j = 0; j < 4; ++j) {
      int d = (col + j) & 127;
      int i = d & 63;
      float partner = lds[(threadIdx.x * 4 + j) ^ 64];
      float c0 = tcs[i], s0 = tsn[i];
      out[j] = (d < 64) ? (out[j] * c0 - partner * s0) : (out[j] * c0 + partner * s0);
    }
  }
  float4 o4 = make_float4(out[0], out[1], out[2], out[3]);
  if (col < 4096)      *(float4*)(q  + (size_t)t * 4096 + col) = o4;
  else if (col < 5120) *(float4*)(kn + (size_t)t * 1024 + (col - 4096)) = o4;
  else                 *(float4*)(vn + (size_t)t * 1024 + (col - 5120)) = o4;
}

// ---------------- kernel 3: flash-decoding attention partials ----------------
// grid (32 seqs, 8 kv-heads, 8 chunks), block 256 (4 waves x 64 positions)
__global__ __launch_bounds__(256) void attn_kernel(
    const float* __restrict__ kcache, const float* __restrict__ vcache,
    const int* __restrict__ bt, const int* __restrict__ ctxl,
    const float* __restrict__ q, const float* __restrict__ kn,
    const float* __restrict__ vn, float* __restrict__ part) {
  const int t = blockIdx.x, kvh = blockIdx.y, ch = blockIdx.z;
  const int ctx = ctxl[t];
  const int s0 = ch * CH;
  if (s0 >= ctx) return;
  const int ns = min(CH, ctx - s0);
  const int tid = threadIdx.x;
  const int w = tid >> 6, lane = tid & 63;

  __shared__ float qs[4][128];
  __shared__ int   bts[16];          // this chunk's 16 block-table entries
  __shared__ float pl[4][64][4];     // [wave][within-wave slot][head]
  __shared__ float om[4][4], ol[4][4];
  __shared__ float oacc[4][4][128];  // [wave][head][d]

  for (int i = tid; i < 512; i += 256)
    qs[i >> 7][i & 127] = q[((size_t)t * NH + kvh * 4 + (i >> 7)) * HD + (i & 127)];
  if (tid < 16) bts[tid] = bt[t * MAXBLK + ch * 16 + tid];   // chunk-local table
  __syncthreads();

  const float* knp = kn + ((size_t)t * NKVH + kvh) * HD;
  const float* vnp = vn + ((size_t)t * NKVH + kvh) * HD;

  // ---- pass 1: 4 positions per wave-step, 16 lanes per position (coalesced rows) ----
  const int j16 = lane & 15;           // dim-slice: covers dims j16*8 .. j16*8+7
  const int pp  = lane >> 4;           // position within step (0..3)
  float4 qa[4], qb[4];
#pragma unroll
  for (int h = 0; h < 4; ++h) {
    qa[h] = *(const float4*)(&qs[h][j16 * 8]);
    qb[h] = *(const float4*)(&qs[h][j16 * 8 + 4]);
  }
#pragma unroll 4
  for (int i = 0; i < 16; ++i) {
    const int ls   = i * 4 + pp;            // within-wave slot 0..63
    const int slp  = w * 64 + ls;           // chunk-local slot 0..255
    const int spos = s0 + slp;              // global position
    const float* kp2;
    {
      int phys = bts[slp >> 4];
      const float* kreal = kcache + (((size_t)phys * BSZ + (slp & 15)) * NKVH + kvh) * HD;
      kp2 = (spos == ctx - 1) ? knp : kreal;  // invalid rows load in-bounds garbage (masked later)
    }
    float4 ka = *(const float4*)(kp2 + j16 * 8);
    float4 kb = *(const float4*)(kp2 + j16 * 8 + 4);
    float d0, d1, d2, d3;
    d0 = ka.x*qa[0].x + ka.y*qa[0].y + ka.z*qa[0].z + ka.w*qa[0].w
       + kb.x*qb[0].x + kb.y*qb[0].y + kb.z*qb[0].z + kb.w*qb[0].w;
    d1 = ka.x*qa[1].x + ka.y*qa[1].y + ka.z*qa[1].z + ka.w*qa[1].w
       + kb.x*qb[1].x + kb.y*qb[1].y + kb.z*qb[1].z + kb.w*qb[1].w;
    d2 = ka.x*qa[2].x + ka.y*qa[2].y + ka.z*qa[2].z + ka.w*qa[2].w
       + kb.x*qb[2].x + kb.y*qb[2].y + kb.z*qb[2].z + kb.w*qb[2].w;
    d3 = ka.x*qa[3].x + ka.y*qa[3].y + ka.z*qa[3].z + ka.w*qa[3].w
       + kb.x*qb[3].x + kb.y*qb[3].y + kb.z*qb[3].z + kb.w*qb[3].w;
#pragma unroll
    for (int m = 1; m < 16; m <<= 1) {
      d0 += __shfl_xor(d0, m, 64);
      d1 += __shfl_xor(d1, m, 64);
      d2 += __shfl_xor(d2, m, 64);
      d3 += __shfl_xor(d3, m, 64);
    }
    if (j16 == 0) *(float4*)&pl[w][ls][0] = make_float4(d0, d1, d2, d3);
  }

  // ---- softmax over 64 positions (reads raw scores from pl; wave-local DS order) ----
  const int sl = w * 64 + lane;
  const bool valid = sl < ns;
  const float scale = 0.08838834764831845f;
  float4 sraw = *(const float4*)&pl[w][lane][0];
  float sc0 = valid ? sraw.x * scale : -INFINITY;
  float sc1 = valid ? sraw.y * scale : -INFINITY;
  float sc2 = valid ? sraw.z * scale : -INFINITY;
  float sc3 = valid ? sraw.w * scale : -INFINITY;

  float m0 = sc0, m1 = sc1, m2 = sc2, m3 = sc3;
#pragma unroll
  for (int mk = 1; mk < 64; mk <<= 1) {
    m0 = fmaxf(m0, __shfl_xor(m0, mk, 64));
    m1 = fmaxf(m1, __shfl_xor(m1, mk, 64));
    m2 = fmaxf(m2, __shfl_xor(m2, mk, 64));
    m3 = fmaxf(m3, __shfl_xor(m3, mk, 64));
  }
  float p0 = __expf(sc0 - fmaxf(m0, -3e38f));
  float p1 = __expf(sc1 - fmaxf(m1, -3e38f));
  float p2 = __expf(sc2 - fmaxf(m2, -3e38f));
  float p3 = __expf(sc3 - fmaxf(m3, -3e38f));
  float l0 = p0, l1 = p1, l2 = p2, l3 = p3;
#pragma unroll
  for (int mk = 1; mk < 64; mk <<= 1) {
    l0 += __shfl_xor(l0, mk, 64);
    l1 += __shfl_xor(l1, mk, 64);
    l2 += __shfl_xor(l2, mk, 64);
    l3 += __shfl_xor(l3, mk, 64);
  }
  *(float4*)&pl[w][lane][0] = make_float4(p0, p1, p2, p3);
  if (lane == 0) {
    om[w][0] = m0; om[w][1] = m1; om[w][2] = m2; om[w][3] = m3;
    ol[w][0] = l0; ol[w][1] = l1; ol[w][2] = l2; ol[w][3] = l3;
  }

  // ---- pass 2: two rows per wave-iter, float4 V loads ----
  const int rh = lane >> 5;
  const int dq = (lane & 31) * 4;
  float a0x=0.f,a0y=0.f,a0z=0.f,a0w=0.f;
  float a1x=0.f,a1y=0.f,a1z=0.f,a1w=0.f;
  float a2x=0.f,a2y=0.f,a2z=0.f,a2w=0.f;
  float a3x=0.f,a3y=0.f,a3z=0.f,a3w=0.f;
  {
    int nsw = ns - w * 64;
    if (nsw > 0) {
      const int sp = (ctx - 1) - (s0 + w * 64);   // special slot, wave-local (may be OOR)
      for (int b4 = 0; b4 < 4; ++b4) {
        int base = b4 * 16;
        if (base >= nsw) break;
        const float* vbase = vcache + (((size_t)bts[w * 4 + b4] * BSZ) * NKVH + kvh) * HD;
#pragma unroll
        for (int j = 0; j < 16; j += 2) {
          int row = base + j + rh;                 // p=0 beyond ns -> garbage*0 OK
          const float* vp = (row == sp) ? vnp : (vbase + (size_t)(j + rh) * (NKVH * HD));
          float4 v4 = *(const float4*)(vp + dq);
          float4 p4 = *(const float4*)&pl[w][row][0];
          a0x = fmaf(p4.x, v4.x, a0x); a0y = fmaf(p4.x, v4.y, a0y);
          a0z = fmaf(p4.x, v4.z, a0z); a0w = fmaf(p4.x, v4.w, a0w);
          a1x = fmaf(p4.y, v4.x, a1x); a1y = fmaf(p4.y, v4.y, a1y);
          a1z = fmaf(p4.y, v4.z, a1z); a1w = fmaf(p4.y, v4.w, a1w);
          a2x = fmaf(p4.z, v4.x, a2x); a2y = fmaf(p4.z, v4.y, a2y);
          a2z = fmaf(p4.z, v4.z, a2z); a2w = fmaf(p4.z, v4.w, a2w);
          a3x = fmaf(p4.w, v4.x, a3x); a3y = fmaf(p4.w, v4.y, a3y);
          a3z = fmaf(p4.w, v4.z, a3z); a3w = fmaf(p4.w, v4.w, a3w);
        }
      }
    }
  }
  a0x += __shfl_xor(a0x, 32, 64); a0y += __shfl_xor(a0y, 32, 64);
  a0z += __shfl_xor(a0z, 32, 64); a0w += __shfl_xor(a0w, 32, 64);
  a1x += __shfl_xor(a1x, 32, 64); a1y += __shfl_xor(a1y, 32, 64);
  a1z += __shfl_xor(a1z, 32, 64); a1w += __shfl_xor(a1w, 32, 64);
  a2x += __shfl_xor(a2x, 32, 64); a2y += __shfl_xor(a2y, 32, 64);
  a2z += __shfl_xor(a2z, 32, 64); a2w += __shfl_xor(a2w, 32, 64);
  a3x += __shfl_xor(a3x, 32, 64); a3y += __shfl_xor(a3y, 32, 64);
  a3z += __shfl_xor(a3z, 32, 64); a3w += __shfl_xor(a3w, 32, 64);
  if (rh == 0) {
    *(float4*)&oacc[w][0][dq] = make_float4(a0x, a0y, a0z, a0w);
    *(float4*)&oacc[w][1][dq] = make_float4(a1x, a1y, a1z, a1w);
    *(float4*)&oacc[w][2][dq] = make_float4(a2x, a2y, a2z, a2w);
    *(float4*)&oacc[w][3][dq] = make_float4(a3x, a3y, a3z, a3w);
  }
  __syncthreads();

  // ---- merge 4 wave-partials, write chunk partial ----
  float* pp2 = part + ((size_t)(t * NKVH + kvh) * 8 + ch) * 520;
  {
    const int g = tid >> 6, d0 = (tid & 63) * 2;
    float mw0 = om[0][g], mw1 = om[1][g], mw2 = om[2][g], mw3 = om[3][g];
    float M = fmaxf(fmaxf(mw0, mw1), fmaxf(mw2, mw3));
    float Ms = fmaxf(M, -3e38f);
    float e0 = __expf(fmaxf(mw0, -3e38f) - Ms);
    float e1 = __expf(fmaxf(mw1, -3e38f) - Ms);
    float e2 = __expf(fmaxf(mw2, -3e38f) - Ms);
    float e3 = __expf(fmaxf(mw3, -3e38f) - Ms);
    float ox = e0*oacc[0][g][d0]   + e1*oacc[1][g][d0]   + e2*oacc[2][g][d0]   + e3*oacc[3][g][d0];
    float oy = e0*oacc[0][g][d0+1] + e1*oacc[1][g][d0+1] + e2*oacc[2][g][d0+1] + e3*oacc[3][g][d0+1];
    *(float2*)(pp2 + 8 + g * 128 + d0) = make_float2(ox, oy);
    if ((tid & 63) == 0) {
      pp2[g]     = M;
      pp2[4 + g] = e0*ol[0][g] + e1*ol[1][g] + e2*ol[2][g] + e3*ol[3][g];
    }
  }
}

// ---------------- kernel 4: combine chunk partials ----------------
__global__ __launch_bounds__(128) void combine_kernel(
    const float* __restrict__ part, const int* __restrict__ ctxl,
    float* __restrict__ attn) {
  const int t = blockIdx.x, kvh = blockIdx.y;
  const int nc = (ctxl[t] + CH - 1) / CH;
  const int d = threadIdx.x;
#pragma unroll
  for (int g = 0; g < 4; ++g) {
    float m = -INFINITY;
    for (int c = 0; c < nc; ++c)
      m = fmaxf(m, part[((size_t)(t * NKVH + kvh) * 8 + c) * 520 + g]);
    float l = 0.f, o = 0.f;
    for (int c = 0; c < nc; ++c) {
      const float* pp = part + ((size_t)(t * NKVH + kvh) * 8 + c) * 520;
      float scl = __expf(pp[g] - m);
      l += pp[4 + g] * scl;
      o += pp[8 + g * 128 + d] * scl;
    }
    attn[((size_t)t * NH + kvh * 4 + g) * HD + d] = o / l;
  }
}

// ---------------- kernel 5: output projection split-K GEMM (R19-exact) ----------------
__global__ __launch_bounds__(256) void proj_kernel(
    const float* __restrict__ attn, const float* __restrict__ Wo,
    float* __restrict__ part) {
  const int lane = threadIdx.x & 63;
  const int wu = __builtin_amdgcn_readfirstlane(threadIdx.x >> 6);
  const int col0 = blockIdx.x * 256 + lane * 4;
  const int kc = blockIdx.y;
  const int k0 = kc * 128;
  float4 acc[8];
#pragma unroll
  for (int r = 0; r < 8; ++r) acc[r] = make_float4(0.f, 0.f, 0.f, 0.f);
  const float* wp = Wo + (size_t)k0 * 4096 + col0;
  const float* hp = attn + (size_t)(wu * 8) * 4096 + k0;
#pragma unroll 4
  for (int kk = 0; kk < 128; ++kk) {
    float4 w4 = *(const float4*)(wp + (size_t)kk * 4096);  // plain load
#pragma unroll
    for (int r = 0; r < 8; ++r) {
      float h = hp[r * 4096 + kk];
      acc[r].x = fmaf(h, w4.x, acc[r].x);
      acc[r].y = fmaf(h, w4.y, acc[r].y);
      acc[r].z = fmaf(h, w4.z, acc[r].z);
      acc[r].w = fmaf(h, w4.w, acc[r].w);
    }
  }
  float* o = part + (size_t)kc * 32 * 4096 + (size_t)(wu * 8) * 4096 + blockIdx.x * 256 + lane * 4;
#pragma unroll
  for (int r = 0; r < 8; ++r) ntstore4(o + (size_t)r * 4096, acc[r]);
}

// ---------------- kernel 6: reduce proj partials -> out ----------------
__global__ __launch_bounds__(256) void reduce_out(
    const float* __restrict__ part, float* __restrict__ out) {
  const int t = blockIdx.x;
  const int col = (blockIdx.y * 256 + threadIdx.x) * 4;
  float4 s0 = make_float4(0.f,0.f,0.f,0.f), s1 = make_float4(0.f,0.f,0.f,0.f);
  const float* p = part + (size_t)t * 4096 + col;
#pragma unroll
  for (int c = 0; c < NKC; c += 2) {
    float4 a = ntload4(p + (size_t)c * 32 * 4096);
    float4 b = ntload4(p + (size_t)(c + 1) * 32 * 4096);
    s0.x += a.x; s0.y += a.y; s0.z += a.z; s0.w += a.w;
    s1.x += b.x; s1.y += b.y; s1.z += b.z; s1.w += b.w;
  }
  float4 s = make_float4(s0.x + s1.x, s0.y + s1.y, s0.z + s1.z, s0.w + s1.w);
  *(float4*)(out + (size_t)t * 4096 + col) = s;
}

extern "C" void kernel_launch(void* const* d_in, const int* in_sizes, int n_in,
                              void* d_out, int out_size, void* d_ws, size_t ws_size,
                              hipStream_t stream) {
  const float* hs = (const float*)d_in[0];
  const float* Wq = (const float*)d_in[1];
  const float* Wk = (const float*)d_in[2];
  const float* Wv = (const float*)d_in[3];
  const float* Wo = (const float*)d_in[4];
  const float* kc = (const float*)d_in[5];
  const float* vc = (const float*)d_in[6];
  const int*   bt = (const int*)d_in[7];
  const int*   cl = (const int*)d_in[8];
  float* out = (float*)d_out;
  float* ws  = (float*)d_ws;

  float* part = ws;
  float* q    = ws + OFF_Q;
  float* kn   = ws + OFF_KN;
  float* vn   = ws + OFF_VN;
  float* at   = ws + OFF_AT;
  float* ap   = ws + OFF_AP;

  qkv_kernel<<<dim3(24, NKC), 256, 0, stream>>>(hs, Wq, Wk, Wv, part);
  rope_kernel<<<dim3(32, 6), 256, 0, stream>>>(part, cl, q, kn, vn);
  attn_kernel<<<dim3(32, 8, 8), 256, 0, stream>>>(kc, vc, bt, cl, q, kn, vn, ap);
  combine_kernel<<<dim3(32, 8), 128, 0, stream>>>(ap, cl, at);
  proj_kernel<<<dim3(16, NKC), 256, 0, stream>>>(at, Wo, part);
  reduce_out<<<dim3(32, 4), 256, 0, stream>>>(part, out);
}